// Round 2
// baseline (136.648 us; speedup 1.0000x reference)
//
#include <hip/hip_runtime.h>

// SoftProjection: B=4, N=8192 points, M=4096 queries, F=64 features, K=16 NN.
// R4: packed-fp32 scan. R3 (121.0us total, 59.2us main) was VALU-issue-bound
// (VALUBusy 81%, MFMA 0, HBM 7%). Both scan passes now evaluate
// val = |p|^2 - 2 q.p with v_pk_fma_f32 (2 points per issue slot, inline asm;
// hipcc never emits VOP3P fp32). Pass A per 4 pts/query: 6 pk_fma + 4 min
// (was 12 fma + 4 min). Pass B: 6 pk_fma + 3-min tree + 1 cmp guard, push
// block only when min(v0..3) <= t (exact skip). fma chain order unchanged =>
// bit-identical vals between passes => threshold proof unchanged.
// Radix select coarsened to top-16 mapped bits (16 iters, bound loosened by
// ~2^-7 rel => ~0.2 extra survivors vs SCAP=54 headroom).
// Structure (R3): QPB=32, QPW=4 wave-pairs, 512 blocks x 1024 thr, LDS 49KB
// => 2 blocks/CU. Epilogue recomputes exact direct-form d2 for softmax.

#define BB 4
#define NN 8192
#define MM 4096
#define FF 64
#define KK 16
#define CHUNK 2048
#define NCHUNK 4
#define QPW 4
#define QPB 32
#define SCAP 54
#define NTHR 1024
#define STG 33

typedef float f2 __attribute__((ext_vector_type(2)));

__device__ __forceinline__ f2 pk_fma(f2 a, f2 b, f2 c) {
    f2 d;
    asm("v_pk_fma_f32 %0, %1, %2, %3" : "=v"(d) : "v"(a), "v"(b), "v"(c));
    return d;
}

__global__ __launch_bounds__(256) void transpose_feat(const float* __restrict__ pf,
                                                      float* __restrict__ pfT) {
    __shared__ float tile[64][65];
    const int b = blockIdx.y;
    const int n0 = blockIdx.x * 64;
    const int t = threadIdx.x;
    const int n = t & 63, fq = t >> 6;
#pragma unroll
    for (int i = 0; i < 16; ++i) {
        int f = fq * 16 + i;
        tile[f][n] = pf[(size_t)b * FF * NN + (size_t)f * NN + n0 + n];
    }
    __syncthreads();
    const int f2i = t & 63, nq = t >> 6;
#pragma unroll
    for (int i = 0; i < 16; ++i) {
        int nn2 = nq * 16 + i;
        pfT[(size_t)b * NN * FF + (size_t)(n0 + nn2) * FF + f2i] = tile[f2i][nn2];
    }
}

__device__ __forceinline__ unsigned mapf(float f) {
    unsigned u = __float_as_uint(f);
    return (u & 0x80000000u) ? ~u : (u | 0x80000000u);
}
__device__ __forceinline__ float unmapf(unsigned k) {
    return (k & 0x80000000u) ? __uint_as_float(k ^ 0x80000000u)
                             : __uint_as_float(~k);
}

// stage chunk C of point cloud into LDS: x, y, z, ps=|p|^2 (512 stager threads)
#define STAGE(C)                                                            \
    do {                                                                    \
        if (t < CHUNK / 4) {                                                \
            int base_ = (C)*CHUNK + t * 4;                                  \
            float4 x4_ = *(const float4*)(pcb + base_);                     \
            float4 y4_ = *(const float4*)(pcb + NN + base_);                \
            float4 z4_ = *(const float4*)(pcb + 2 * NN + base_);            \
            *(float4*)(s_pts + t * 4) = x4_;                                \
            *(float4*)(s_pts + CHUNK + t * 4) = y4_;                        \
            *(float4*)(s_pts + 2 * CHUNK + t * 4) = z4_;                    \
            float4 p4_;                                                     \
            p4_.x = fmaf(x4_.x, x4_.x, fmaf(y4_.x, y4_.x, z4_.x * z4_.x));  \
            p4_.y = fmaf(x4_.y, x4_.y, fmaf(y4_.y, y4_.y, z4_.y * z4_.y));  \
            p4_.z = fmaf(x4_.z, x4_.z, fmaf(y4_.z, y4_.z, z4_.z * z4_.z));  \
            p4_.w = fmaf(x4_.w, x4_.w, fmaf(y4_.w, y4_.w, z4_.w * z4_.w));  \
            *(float4*)(s_pts + 3 * CHUNK + t * 4) = p4_;                    \
        }                                                                   \
    } while (0)

// packed val for 2 points: fma(x,qx, fma(y,qy, fma(z,qz, ps))) per half.
// identical chain order to scalar fmaf form => bit-deterministic across passes
#define VAL2(XY, YY, ZY, PY, Q) \
    pk_fma((XY), qx2p[Q], pk_fma((YY), qy2p[Q], pk_fma((ZY), qz2p[Q], (PY))))

#define PUSH(WQ, V, I)                                          \
    do {                                                        \
        int pos_ = atomicAdd(&s_cnt[WQ], 1);                    \
        if (pos_ < SCAP) {                                      \
            s_surv[((WQ)*SCAP + pos_) * 2] = (V);               \
            s_surv[((WQ)*SCAP + pos_) * 2 + 1] = __int_as_float(I); \
        }                                                       \
    } while (0)

__global__ __launch_bounds__(NTHR, 8) void soft_proj_kernel(
    const float* __restrict__ pc, const float* __restrict__ qc,
    const float* __restrict__ pf, const float* __restrict__ pfT,
    const float* __restrict__ temp, float* __restrict__ out, int useT) {
    __shared__ __align__(16) float s_pts[4 * CHUNK];        // 32768 B
    __shared__ __align__(16) float s_surv[QPB * SCAP * 2];  // 13824 B (val,idx)
    __shared__ int s_cnt[QPB];                              // 128 B
    __shared__ int s_sel[QPB * KK];                         // 2048 B
    __shared__ float s_thr[2 * QPB];                        // 256 B => 49024 B

    const int bid = blockIdx.x;
    const int b = bid >> 7;               // 128 blocks per batch
    const int m0 = (bid & 127) * QPB;
    const int t = threadIdx.x;
    const int wave = t >> 6;              // 16 waves
    const int lane = t & 63;
    const int pairIdx = wave & 7;         // 8 wave-pairs x QPW=4 queries = 32
    const int half = wave >> 3;           // which point-half this wave scans

    const float* pcb = pc + (size_t)b * 3 * NN;
    const float* qcb = qc + (size_t)b * 3 * MM;

    // scan-phase query constants: -2*q, broadcast into both packed halves
    f2 qx2p[QPW], qy2p[QPW], qz2p[QPW];
#pragma unroll
    for (int q = 0; q < QPW; ++q) {
        int m = m0 + pairIdx * QPW + q;
        float qx = -2.0f * qcb[m];
        float qy = -2.0f * qcb[MM + m];
        float qz = -2.0f * qcb[2 * MM + m];
        qx2p[q] = (f2){qx, qx};
        qy2p[q] = (f2){qy, qy};
        qz2p[q] = (f2){qz, qz};
    }

    float mn[QPW];
#pragma unroll
    for (int q = 0; q < QPW; ++q) mn[q] = 3.0e38f;

    // ---------------- pass A: per-lane min of val over 64 points ------------
    for (int c = 0; c < NCHUNK; ++c) {
        __syncthreads();
        STAGE(c);
        __syncthreads();
        const int ob = half * 1024 + lane * 4;
#pragma unroll
        for (int g = 0; g < 4; ++g) {
            int oo = ob + g * 256;
            float4 x4 = *(const float4*)(s_pts + oo);
            float4 y4 = *(const float4*)(s_pts + CHUNK + oo);
            float4 z4 = *(const float4*)(s_pts + 2 * CHUNK + oo);
            float4 p4 = *(const float4*)(s_pts + 3 * CHUNK + oo);
            f2 xlo = (f2){x4.x, x4.y}, xhi = (f2){x4.z, x4.w};
            f2 ylo = (f2){y4.x, y4.y}, yhi = (f2){y4.z, y4.w};
            f2 zlo = (f2){z4.x, z4.y}, zhi = (f2){z4.z, z4.w};
            f2 plo = (f2){p4.x, p4.y}, phi = (f2){p4.z, p4.w};
#pragma unroll
            for (int q = 0; q < QPW; ++q) {
                f2 v01 = VAL2(xlo, ylo, zlo, plo, q);
                f2 v23 = VAL2(xhi, yhi, zhi, phi, q);
                float m01 = fminf(v01.x, v01.y);
                float m23 = fminf(v23.x, v23.y);
                mn[q] = fminf(mn[q], fminf(m01, m23));
            }
        }
    }

    // ---- per-wave radix select: 8th-smallest of 64 lane minima (per query) --
    // coarse: top 16 mapped bits; res|0xFFFF still a provable upper bound
    float thrv[QPW];
#pragma unroll
    for (int q = 0; q < QPW; ++q) {
        unsigned key = mapf(mn[q]);
        unsigned res = 0u;
        for (int bb = 31; bb >= 16; --bb) {
            unsigned cand = res | (1u << bb);
            unsigned long long bal = __ballot(key < cand);
            int c2 = __popcll(bal);
            if (c2 < 8) res = cand;  // 8th smallest has this bit set
        }
        thrv[q] = unmapf(res | 0xFFFFu);  // upper bound on 8th smallest
    }
    if (lane == 0) {
#pragma unroll
        for (int q = 0; q < QPW; ++q)
            s_thr[half * QPB + pairIdx * QPW + q] = thrv[q];
    }
    if (t < QPB) s_cnt[t] = 0;
    __syncthreads();
    // t = max(tA8, tB8): >=8 points <= t in each half => >=16 total => valid
    // upper bound on the true 16th-smallest val.
#pragma unroll
    for (int q = 0; q < QPW; ++q)
        thrv[q] = fmaxf(s_thr[pairIdx * QPW + q], s_thr[QPB + pairIdx * QPW + q]);

    // ---------------- pass B: collect survivors val <= t --------------------
    for (int c = 0; c < NCHUNK; ++c) {
        __syncthreads();
        STAGE(c);
        __syncthreads();
        const int ob = half * 1024 + lane * 4;
#pragma unroll
        for (int g = 0; g < 4; ++g) {
            int oo = ob + g * 256;
            float4 x4 = *(const float4*)(s_pts + oo);
            float4 y4 = *(const float4*)(s_pts + CHUNK + oo);
            float4 z4 = *(const float4*)(s_pts + 2 * CHUNK + oo);
            float4 p4 = *(const float4*)(s_pts + 3 * CHUNK + oo);
            f2 xlo = (f2){x4.x, x4.y}, xhi = (f2){x4.z, x4.w};
            f2 ylo = (f2){y4.x, y4.y}, yhi = (f2){y4.z, y4.w};
            f2 zlo = (f2){z4.x, z4.y}, zhi = (f2){z4.z, z4.w};
            f2 plo = (f2){p4.x, p4.y}, phi = (f2){p4.z, p4.w};
            int gi = c * CHUNK + oo;
#pragma unroll
            for (int q = 0; q < QPW; ++q) {
                f2 v01 = VAL2(xlo, ylo, zlo, plo, q);
                f2 v23 = VAL2(xhi, yhi, zhi, phi, q);
                float m01 = fminf(v01.x, v01.y);
                float m23 = fminf(v23.x, v23.y);
                // exact skip: min > t => every element > t
                if (fminf(m01, m23) <= thrv[q]) {
                    int wqq = pairIdx * QPW + q;
                    if (v01.x <= thrv[q]) PUSH(wqq, v01.x, gi + 0);
                    if (v01.y <= thrv[q]) PUSH(wqq, v01.y, gi + 1);
                    if (v23.x <= thrv[q]) PUSH(wqq, v23.x, gi + 2);
                    if (v23.y <= thrv[q]) PUSH(wqq, v23.y, gi + 3);
                }
            }
        }
    }
    __syncthreads();

    // ------------- exact select: rank survivors by (val, idx) ---------------
#pragma unroll
    for (int qq = 0; qq < 2; ++qq) {
        int wq = wave * 2 + qq;           // 16 waves x 2 = 32 queries
        int cnt = s_cnt[wq];
        cnt = __builtin_amdgcn_readfirstlane(cnt);
        if (cnt > SCAP) cnt = SCAP;
        bool valid = lane < cnt;
        float mv = 0.f;
        int mi = 0;
        if (valid) {
            mv = s_surv[(wq * SCAP + lane) * 2];
            mi = __float_as_int(s_surv[(wq * SCAP + lane) * 2 + 1]);
        }
        int rank = 0;
        for (int j = 0; j < cnt; ++j) {
            float vj = s_surv[(wq * SCAP + j) * 2];
            int ij = __float_as_int(s_surv[(wq * SCAP + j) * 2 + 1]);
            if (valid && (vj < mv || (vj == mv && ij < mi))) rank++;
        }
        if (valid && rank < KK) s_sel[wq * KK + rank] = mi;
    }
    __syncthreads();  // survivors dead; s_surv becomes the output stage

    // ---------------- softmax + gather + accumulate -------------------------
    float* stage = s_surv;  // [67 rows][STG=33 cols]
    float tval = temp[0];
    float sigma = fmaxf(tval * tval, 1.0e-4f);
    float inv_sigma = 1.0f / sigma;
    const float* pfTb = pfT + (size_t)b * NN * FF;
    const float* pfb = pf + (size_t)b * FF * NN;

#pragma unroll
    for (int qq = 0; qq < 2; ++qq) {
        int wq = wave * 2 + qq;
        int m = m0 + wq;
        float qxe = qcb[m], qye = qcb[MM + m], qze = qcb[2 * MM + m];
        int ik[KK];
        float dk[KK];
#pragma unroll
        for (int k = 0; k < KK; ++k) {
            int ii = __builtin_amdgcn_readfirstlane(s_sel[wq * KK + k]);
            ik[k] = ii;
            float px = pcb[ii], py = pcb[NN + ii], pz = pcb[2 * NN + ii];
            float dx = px - qxe, dy = py - qye, dz = pz - qze;
            dk[k] = fmaf(dx, dx, fmaf(dy, dy, dz * dz));  // exact direct form
        }
        float dmin = dk[0];
#pragma unroll
        for (int k = 1; k < KK; ++k) dmin = fminf(dmin, dk[k]);
        float ssum = 0.f, facc = 0.f, sx = 0.f, sy = 0.f, sz = 0.f;
#pragma unroll
        for (int k = 0; k < KK; ++k) {
            float e = __expf((dmin - dk[k]) * inv_sigma);
            ssum += e;
            float px = pcb[ik[k]], py = pcb[NN + ik[k]], pz = pcb[2 * NN + ik[k]];
            sx = fmaf(e, px, sx);
            sy = fmaf(e, py, sy);
            sz = fmaf(e, pz, sz);
            float fv = useT ? pfTb[(size_t)ik[k] * FF + lane]
                            : pfb[(size_t)lane * NN + ik[k]];
            facc = fmaf(e, fv, facc);
        }
        float rs = 1.0f / ssum;
        stage[lane * STG + wq] = facc * rs;
        if (lane == 0) {
            stage[(64) * STG + wq] = sx * rs;
            stage[(65) * STG + wq] = sy * rs;
            stage[(66) * STG + wq] = sz * rs;
        }
    }
    __syncthreads();

    // ---------------- coalesced write-out -----------------------------------
    const size_t featOff = (size_t)BB * 3 * MM;
    for (int j = t; j < 67 * QPB; j += NTHR) {
        int row = j >> 5, col = j & 31;
        float v = stage[row * STG + col];
        int m = m0 + col;
        if (row < 64)
            out[featOff + (size_t)b * FF * MM + (size_t)row * MM + m] = v;
        else
            out[(size_t)b * 3 * MM + (size_t)(row - 64) * MM + m] = v;
    }
}

extern "C" void kernel_launch(void* const* d_in, const int* in_sizes, int n_in,
                              void* d_out, int out_size, void* d_ws, size_t ws_size,
                              hipStream_t stream) {
    (void)in_sizes; (void)n_in; (void)out_size;
    const float* pc = (const float*)d_in[0];
    const float* qc = (const float*)d_in[1];
    const float* pf = (const float*)d_in[2];
    const float* temp = (const float*)d_in[3];
    float* out = (float*)d_out;
    float* pfT = (float*)d_ws;
    const size_t needT = (size_t)BB * NN * FF * sizeof(float);  // 8 MB
    int useT = (ws_size >= needT && d_ws != nullptr) ? 1 : 0;

    if (useT) {
        hipLaunchKernelGGL(transpose_feat, dim3(NN / 64, BB), dim3(256), 0, stream,
                           pf, pfT);
    }
    hipLaunchKernelGGL(soft_proj_kernel, dim3((BB * MM) / QPB), dim3(NTHR), 0,
                       stream, pc, qc, pf, pfT, temp, out, useT);
}

// Round 3
// 119.510 us; speedup vs baseline: 1.1434x; 1.1434x over previous
//
#include <hip/hip_runtime.h>

// SoftProjection: B=4, N=8192 points, M=4096 queries, F=64 features, K=16 NN.
// R5: revert R4's inline-asm v_pk_fma_f32 scan (it spilled to scratch:
// +38MB HBM traffic, VALUBusy 81->54, kernel 59->77us -- VGPR pair-alignment
// pressure from 20+ ext_vector asm operands). Back to R3's scalar scan
// (known 59.2us), keeping two validated/safe trims:
//  - radix select on top-16 mapped bits (16 iters, was 24); threshold still a
//    provable upper bound on the 8th-smallest lane-min (validated in R4 run).
//  - pass-B whole-group skip guard: 3-min tree + one branch; push block only
//    when min(v0..v3) <= t (exact skip, ~54% of wave-iterations skip fully).
// Structure (R3): QPB=32, QPW=4 wave-pairs, 512 blocks x 1024 thr, LDS 49KB
// => 2 blocks/CU. Pass A: val = |p|^2 - 2 q.p per-lane min; per-wave
// radix/ballot 8th-smallest; t = max over point-halves => >=16 pts <= t.
// Pass B: collect survivors (E~20, cap 54), exact rank by (val,idx).
// Epilogue recomputes exact direct-form d2 for softmax (matches reference).

#define BB 4
#define NN 8192
#define MM 4096
#define FF 64
#define KK 16
#define CHUNK 2048
#define NCHUNK 4
#define QPW 4
#define QPB 32
#define SCAP 54
#define NTHR 1024
#define STG 33

__global__ __launch_bounds__(256) void transpose_feat(const float* __restrict__ pf,
                                                      float* __restrict__ pfT) {
    __shared__ float tile[64][65];
    const int b = blockIdx.y;
    const int n0 = blockIdx.x * 64;
    const int t = threadIdx.x;
    const int n = t & 63, fq = t >> 6;
#pragma unroll
    for (int i = 0; i < 16; ++i) {
        int f = fq * 16 + i;
        tile[f][n] = pf[(size_t)b * FF * NN + (size_t)f * NN + n0 + n];
    }
    __syncthreads();
    const int f2 = t & 63, nq = t >> 6;
#pragma unroll
    for (int i = 0; i < 16; ++i) {
        int nn2 = nq * 16 + i;
        pfT[(size_t)b * NN * FF + (size_t)(n0 + nn2) * FF + f2] = tile[f2][nn2];
    }
}

__device__ __forceinline__ unsigned mapf(float f) {
    unsigned u = __float_as_uint(f);
    return (u & 0x80000000u) ? ~u : (u | 0x80000000u);
}
__device__ __forceinline__ float unmapf(unsigned k) {
    return (k & 0x80000000u) ? __uint_as_float(k ^ 0x80000000u)
                             : __uint_as_float(~k);
}

// stage chunk C of point cloud into LDS: x, y, z, ps=|p|^2 (512 stager threads)
#define STAGE(C)                                                            \
    do {                                                                    \
        if (t < CHUNK / 4) {                                                \
            int base_ = (C)*CHUNK + t * 4;                                  \
            float4 x4_ = *(const float4*)(pcb + base_);                     \
            float4 y4_ = *(const float4*)(pcb + NN + base_);                \
            float4 z4_ = *(const float4*)(pcb + 2 * NN + base_);            \
            *(float4*)(s_pts + t * 4) = x4_;                                \
            *(float4*)(s_pts + CHUNK + t * 4) = y4_;                        \
            *(float4*)(s_pts + 2 * CHUNK + t * 4) = z4_;                    \
            float4 p4_;                                                     \
            p4_.x = fmaf(x4_.x, x4_.x, fmaf(y4_.x, y4_.x, z4_.x * z4_.x));  \
            p4_.y = fmaf(x4_.y, x4_.y, fmaf(y4_.y, y4_.y, z4_.y * z4_.y));  \
            p4_.z = fmaf(x4_.z, x4_.z, fmaf(y4_.z, y4_.z, z4_.z * z4_.z));  \
            p4_.w = fmaf(x4_.w, x4_.w, fmaf(y4_.w, y4_.w, z4_.w * z4_.w));  \
            *(float4*)(s_pts + 3 * CHUNK + t * 4) = p4_;                    \
        }                                                                   \
    } while (0)

// identical val expression in both passes (explicit fmaf => bit-deterministic)
#define VAL(X, Y, Z, PS, Q) \
    fmaf((X), qx2[Q], fmaf((Y), qy2[Q], fmaf((Z), qz2[Q], (PS))))

#define PUSH(WQ, V, I)                                          \
    do {                                                        \
        int pos_ = atomicAdd(&s_cnt[WQ], 1);                    \
        if (pos_ < SCAP) {                                      \
            s_surv[((WQ)*SCAP + pos_) * 2] = (V);               \
            s_surv[((WQ)*SCAP + pos_) * 2 + 1] = __int_as_float(I); \
        }                                                       \
    } while (0)

__global__ __launch_bounds__(NTHR, 8) void soft_proj_kernel(
    const float* __restrict__ pc, const float* __restrict__ qc,
    const float* __restrict__ pf, const float* __restrict__ pfT,
    const float* __restrict__ temp, float* __restrict__ out, int useT) {
    __shared__ __align__(16) float s_pts[4 * CHUNK];        // 32768 B
    __shared__ __align__(16) float s_surv[QPB * SCAP * 2];  // 13824 B (val,idx)
    __shared__ int s_cnt[QPB];                              // 128 B
    __shared__ int s_sel[QPB * KK];                         // 2048 B
    __shared__ float s_thr[2 * QPB];                        // 256 B => 49024 B

    const int bid = blockIdx.x;
    const int b = bid >> 7;               // 128 blocks per batch
    const int m0 = (bid & 127) * QPB;
    const int t = threadIdx.x;
    const int wave = t >> 6;              // 16 waves
    const int lane = t & 63;
    const int pairIdx = wave & 7;         // 8 wave-pairs x QPW=4 queries = 32
    const int half = wave >> 3;           // which point-half this wave scans

    const float* pcb = pc + (size_t)b * 3 * NN;
    const float* qcb = qc + (size_t)b * 3 * MM;

    // scan-phase query constants: -2*q
    float qx2[QPW], qy2[QPW], qz2[QPW];
#pragma unroll
    for (int q = 0; q < QPW; ++q) {
        int m = m0 + pairIdx * QPW + q;
        qx2[q] = -2.0f * qcb[m];
        qy2[q] = -2.0f * qcb[MM + m];
        qz2[q] = -2.0f * qcb[2 * MM + m];
    }

    float mn[QPW];
#pragma unroll
    for (int q = 0; q < QPW; ++q) mn[q] = 3.0e38f;

    // ---------------- pass A: per-lane min of val over 64 points ------------
    for (int c = 0; c < NCHUNK; ++c) {
        __syncthreads();
        STAGE(c);
        __syncthreads();
        const int ob = half * 1024 + lane * 4;
#pragma unroll
        for (int g = 0; g < 4; ++g) {
            int oo = ob + g * 256;
            float4 x4 = *(const float4*)(s_pts + oo);
            float4 y4 = *(const float4*)(s_pts + CHUNK + oo);
            float4 z4 = *(const float4*)(s_pts + 2 * CHUNK + oo);
            float4 p4 = *(const float4*)(s_pts + 3 * CHUNK + oo);
#pragma unroll
            for (int q = 0; q < QPW; ++q) {
                float v0 = VAL(x4.x, y4.x, z4.x, p4.x, q);
                float v1 = VAL(x4.y, y4.y, z4.y, p4.y, q);
                float v2 = VAL(x4.z, y4.z, z4.z, p4.z, q);
                float v3 = VAL(x4.w, y4.w, z4.w, p4.w, q);
                mn[q] = fminf(mn[q], fminf(fminf(v0, v1), fminf(v2, v3)));
            }
        }
    }

    // ---- per-wave radix select: 8th-smallest of 64 lane minima (per query) --
    // coarse: top 16 mapped bits; res|0xFFFF still a provable upper bound
    float thrv[QPW];
#pragma unroll
    for (int q = 0; q < QPW; ++q) {
        unsigned key = mapf(mn[q]);
        unsigned res = 0u;
        for (int bb = 31; bb >= 16; --bb) {
            unsigned cand = res | (1u << bb);
            unsigned long long bal = __ballot(key < cand);
            int c2 = __popcll(bal);
            if (c2 < 8) res = cand;  // 8th smallest has this bit set
        }
        thrv[q] = unmapf(res | 0xFFFFu);  // upper bound on 8th smallest
    }
    if (lane == 0) {
#pragma unroll
        for (int q = 0; q < QPW; ++q)
            s_thr[half * QPB + pairIdx * QPW + q] = thrv[q];
    }
    if (t < QPB) s_cnt[t] = 0;
    __syncthreads();
    // t = max(tA8, tB8): >=8 points <= t in each half => >=16 total => valid
    // upper bound on the true 16th-smallest val.
#pragma unroll
    for (int q = 0; q < QPW; ++q)
        thrv[q] = fmaxf(s_thr[pairIdx * QPW + q], s_thr[QPB + pairIdx * QPW + q]);

    // ---------------- pass B: collect survivors val <= t --------------------
    for (int c = 0; c < NCHUNK; ++c) {
        __syncthreads();
        STAGE(c);
        __syncthreads();
        const int ob = half * 1024 + lane * 4;
#pragma unroll
        for (int g = 0; g < 4; ++g) {
            int oo = ob + g * 256;
            float4 x4 = *(const float4*)(s_pts + oo);
            float4 y4 = *(const float4*)(s_pts + CHUNK + oo);
            float4 z4 = *(const float4*)(s_pts + 2 * CHUNK + oo);
            float4 p4 = *(const float4*)(s_pts + 3 * CHUNK + oo);
            int gi = c * CHUNK + oo;
#pragma unroll
            for (int q = 0; q < QPW; ++q) {
                float v0 = VAL(x4.x, y4.x, z4.x, p4.x, q);
                float v1 = VAL(x4.y, y4.y, z4.y, p4.y, q);
                float v2 = VAL(x4.z, y4.z, z4.z, p4.z, q);
                float v3 = VAL(x4.w, y4.w, z4.w, p4.w, q);
                float m01 = fminf(v0, v1);
                float m23 = fminf(v2, v3);
                // exact whole-group skip: min > t => every element > t
                if (fminf(m01, m23) <= thrv[q]) {
                    int wqq = pairIdx * QPW + q;
                    if (v0 <= thrv[q]) PUSH(wqq, v0, gi + 0);
                    if (v1 <= thrv[q]) PUSH(wqq, v1, gi + 1);
                    if (v2 <= thrv[q]) PUSH(wqq, v2, gi + 2);
                    if (v3 <= thrv[q]) PUSH(wqq, v3, gi + 3);
                }
            }
        }
    }
    __syncthreads();

    // ------------- exact select: rank survivors by (val, idx) ---------------
#pragma unroll
    for (int qq = 0; qq < 2; ++qq) {
        int wq = wave * 2 + qq;           // 16 waves x 2 = 32 queries
        int cnt = s_cnt[wq];
        cnt = __builtin_amdgcn_readfirstlane(cnt);
        if (cnt > SCAP) cnt = SCAP;
        bool valid = lane < cnt;
        float mv = 0.f;
        int mi = 0;
        if (valid) {
            mv = s_surv[(wq * SCAP + lane) * 2];
            mi = __float_as_int(s_surv[(wq * SCAP + lane) * 2 + 1]);
        }
        int rank = 0;
        for (int j = 0; j < cnt; ++j) {
            float vj = s_surv[(wq * SCAP + j) * 2];
            int ij = __float_as_int(s_surv[(wq * SCAP + j) * 2 + 1]);
            if (valid && (vj < mv || (vj == mv && ij < mi))) rank++;
        }
        if (valid && rank < KK) s_sel[wq * KK + rank] = mi;
    }
    __syncthreads();  // survivors dead; s_surv becomes the output stage

    // ---------------- softmax + gather + accumulate -------------------------
    float* stage = s_surv;  // [67 rows][STG=33 cols]
    float tval = temp[0];
    float sigma = fmaxf(tval * tval, 1.0e-4f);
    float inv_sigma = 1.0f / sigma;
    const float* pfTb = pfT + (size_t)b * NN * FF;
    const float* pfb = pf + (size_t)b * FF * NN;

#pragma unroll
    for (int qq = 0; qq < 2; ++qq) {
        int wq = wave * 2 + qq;
        int m = m0 + wq;
        float qxe = qcb[m], qye = qcb[MM + m], qze = qcb[2 * MM + m];
        int ik[KK];
        float dk[KK];
#pragma unroll
        for (int k = 0; k < KK; ++k) {
            int ii = __builtin_amdgcn_readfirstlane(s_sel[wq * KK + k]);
            ik[k] = ii;
            float px = pcb[ii], py = pcb[NN + ii], pz = pcb[2 * NN + ii];
            float dx = px - qxe, dy = py - qye, dz = pz - qze;
            dk[k] = fmaf(dx, dx, fmaf(dy, dy, dz * dz));  // exact direct form
        }
        float dmin = dk[0];
#pragma unroll
        for (int k = 1; k < KK; ++k) dmin = fminf(dmin, dk[k]);
        float ssum = 0.f, facc = 0.f, sx = 0.f, sy = 0.f, sz = 0.f;
#pragma unroll
        for (int k = 0; k < KK; ++k) {
            float e = __expf((dmin - dk[k]) * inv_sigma);
            ssum += e;
            float px = pcb[ik[k]], py = pcb[NN + ik[k]], pz = pcb[2 * NN + ik[k]];
            sx = fmaf(e, px, sx);
            sy = fmaf(e, py, sy);
            sz = fmaf(e, pz, sz);
            float fv = useT ? pfTb[(size_t)ik[k] * FF + lane]
                            : pfb[(size_t)lane * NN + ik[k]];
            facc = fmaf(e, fv, facc);
        }
        float rs = 1.0f / ssum;
        stage[lane * STG + wq] = facc * rs;
        if (lane == 0) {
            stage[(64) * STG + wq] = sx * rs;
            stage[(65) * STG + wq] = sy * rs;
            stage[(66) * STG + wq] = sz * rs;
        }
    }
    __syncthreads();

    // ---------------- coalesced write-out -----------------------------------
    const size_t featOff = (size_t)BB * 3 * MM;
    for (int j = t; j < 67 * QPB; j += NTHR) {
        int row = j >> 5, col = j & 31;
        float v = stage[row * STG + col];
        int m = m0 + col;
        if (row < 64)
            out[featOff + (size_t)b * FF * MM + (size_t)row * MM + m] = v;
        else
            out[(size_t)b * 3 * MM + (size_t)(row - 64) * MM + m] = v;
    }
}

extern "C" void kernel_launch(void* const* d_in, const int* in_sizes, int n_in,
                              void* d_out, int out_size, void* d_ws, size_t ws_size,
                              hipStream_t stream) {
    (void)in_sizes; (void)n_in; (void)out_size;
    const float* pc = (const float*)d_in[0];
    const float* qc = (const float*)d_in[1];
    const float* pf = (const float*)d_in[2];
    const float* temp = (const float*)d_in[3];
    float* out = (float*)d_out;
    float* pfT = (float*)d_ws;
    const size_t needT = (size_t)BB * NN * FF * sizeof(float);  // 8 MB
    int useT = (ws_size >= needT && d_ws != nullptr) ? 1 : 0;

    if (useT) {
        hipLaunchKernelGGL(transpose_feat, dim3(NN / 64, BB), dim3(256), 0, stream,
                           pf, pfT);
    }
    hipLaunchKernelGGL(soft_proj_kernel, dim3((BB * MM) / QPB), dim3(NTHR), 0,
                       stream, pc, qc, pf, pfT, temp, out, useT);
}